// Round 5
// baseline (161.933 us; speedup 1.0000x reference)
//
#include <hip/hip_runtime.h>
#include <hip/hip_bf16.h>
#include <hip/hip_fp16.h>
#include <cmath>

#define NF 64
#define GRP 8
#define CG 8
#define KK 9
#define HH 128
#define WWID 128
#define BB 4
#define HWSZ (HH * WWID)
#define C_OM 216
#define OMS 226   // fp16 LDS stride (113 dwords -> conflict-free pixel stride)

typedef __attribute__((ext_vector_type(8))) short bf16x8;
typedef __attribute__((ext_vector_type(4))) float f32x4;

__device__ inline unsigned short f2bf(float f) {
    union { float f; unsigned u; } x; x.f = f;
    unsigned r = x.u + 0x7fff + ((x.u >> 16) & 1);   // RNE
    return (unsigned short)(r >> 16);
}
__device__ inline float bf2f(unsigned short s) {
    union { unsigned u; float f; } x; x.u = ((unsigned)s) << 16; return x.f;
}

// ---------------------------------------------------------------------------
// NCHW fp32 (nbr ++ ref) -> NHWC bf16 [B][H][W][128] + compact nbr NHWC64
// ---------------------------------------------------------------------------
__global__ __launch_bounds__(256) void to_nhwc_kernel(
    const float* __restrict__ nbr, const float* __restrict__ ref,
    unsigned short* __restrict__ out, unsigned short* __restrict__ out64)
{
    __shared__ unsigned short lds[64 * 132];
    const int tid = threadIdx.x, blk = blockIdx.x;
    const int b = blk >> 8, rem = blk & 255, y = rem >> 1, x0 = (rem & 1) * 64;
    const size_t rowoff = (size_t)y * WWID + x0;

    for (int it = 0; it < 32; ++it) {
        int idx = it * 256 + tid;
        int c = idx >> 6, p = idx & 63;
        const float* src = (c < NF) ? (nbr + (size_t)(b * NF + c) * HWSZ)
                                    : (ref + (size_t)(b * NF + c - NF) * HWSZ);
        lds[p * 132 + c] = f2bf(src[rowoff + p]);
    }
    __syncthreads();
    const int p = tid >> 2, c0 = (tid & 3) * 32;
    unsigned short* dst = out + ((size_t)b * HWSZ + rowoff + p) * 128 + c0;
#pragma unroll
    for (int i = 0; i < 8; ++i)
        *(int2*)(dst + i * 4) = *(const int2*)&lds[p * 132 + c0 + i * 4];
    if (c0 < 64) {
        unsigned short* dst2 = out64 + ((size_t)b * HWSZ + rowoff + p) * 64 + c0;
#pragma unroll
        for (int i = 0; i < 8; ++i)
            *(int2*)(dst2 + i * 4) = *(const int2*)&lds[p * 132 + c0 + i * 4];
    }
}

// ---------------------------------------------------------------------------
// All weight repacks in one launch.
// wf1: conv1 A-frags (CIN=128, COUT=64, MT=4),   73728 elems
// wf2: om   A-frags (CIN=64, COUT=216, MT=14),  129024 elems
// wdf: dcn  A-frags (K=(g*9+kt)*8+c),            36864 elems
// ---------------------------------------------------------------------------
__global__ void repack_all_kernel(const float* __restrict__ w1,
                                  const float* __restrict__ wom,
                                  const float* __restrict__ wdcn,
                                  unsigned short* __restrict__ wf1,
                                  unsigned short* __restrict__ wf2,
                                  unsigned short* __restrict__ wdf)
{
    int idx = blockIdx.x * 256 + threadIdx.x;
    if (idx < 73728) {
        int j = idx & 7, lane = (idx >> 3) & 63, t = idx >> 9;
        int mt = t % 4, kt = t / 4;
        int c0 = (kt / 9) * 32, tap = kt - (kt / 9) * 9;
        int cout = mt * 16 + (lane & 15);
        int cin = c0 + ((lane >> 4) * 8) + j;
        wf1[idx] = f2bf(w1[((size_t)cout * 128 + cin) * KK + tap]);
        return;
    }
    idx -= 73728;
    if (idx < 129024) {
        int j = idx & 7, lane = (idx >> 3) & 63, t = idx >> 9;
        int mt = t % 14, kt = t / 14;
        int c0 = (kt / 9) * 32, tap = kt - (kt / 9) * 9;
        int cout = mt * 16 + (lane & 15);
        int cin = c0 + ((lane >> 4) * 8) + j;
        float v = (cout < C_OM) ? wom[((size_t)cout * 64 + cin) * KK + tap] : 0.f;
        wf2[idx] = f2bf(v);
        return;
    }
    idx -= 129024;
    if (idx < 36864) {
        int j = idx & 7, lane = (idx >> 3) & 63, t = idx >> 9;
        int mt = t & 3, s = t >> 2;
        int cout = mt * 16 + (lane & 15);
        int kglob = s * 32 + (lane >> 4) * 8 + j;
        int gk = kglob >> 3, c = kglob & 7;
        int g = gk / 9, kt = gk - g * 9;
        wdf[idx] = f2bf(wdcn[((size_t)cout * NF + g * 8 + c) * 9 + kt]);
    }
}

// ---------------------------------------------------------------------------
// Implicit-GEMM 3x3 conv (conv1) via mfma_f32_16x16x32_bf16.
// ---------------------------------------------------------------------------
template <int CIN, int COUT, bool LRELU, int NT>
__global__ __launch_bounds__(256) void conv_mfma_kernel(
    const unsigned short* __restrict__ in,
    const unsigned short* __restrict__ wf,
    const float* __restrict__ bias,
    unsigned short* __restrict__ dst)
{
    const int tid = threadIdx.x;
    const int lane = tid & 63;
    const int wv = tid >> 6;
    const int ng = blockIdx.x * 4 + wv;
    constexpr int SEG = 128 / (16 * NT);
    const int x0 = (ng % SEG) * (16 * NT);
    const int y  = (ng / SEG) % 128;
    const int b  = ng / (SEG * 128);
    const int ln = lane & 15, kb = lane >> 4;

    f32x4 acc[4][NT];
#pragma unroll
    for (int i = 0; i < 4; ++i)
#pragma unroll
        for (int j = 0; j < NT; ++j) acc[i][j] = f32x4{0.f, 0.f, 0.f, 0.f};

    const unsigned short* inb = in + (size_t)b * HWSZ * CIN + (size_t)kb * 8;

    for (int c0 = 0; c0 < CIN; c0 += 32) {
#pragma unroll
        for (int tap = 0; tap < 9; ++tap) {
            const int ky = tap / 3, kx = tap % 3;
            const int yy = y + ky - 1;
            const bool rowv = (unsigned)yy < (unsigned)HH;
            const int yc = rowv ? yy : 0;
            const unsigned short* rowp = inb + (size_t)yc * WWID * CIN + c0;
            bf16x8 bfrag[NT];
#pragma unroll
            for (int nt = 0; nt < NT; ++nt) {
                int xx = x0 + nt * 16 + ln + kx - 1;
                bool v = rowv && ((unsigned)xx < (unsigned)WWID);
                int xc = v ? xx : 0;
                int4 t = *(const int4*)(rowp + (size_t)xc * CIN);
                if (!v) { t.x = 0; t.y = 0; t.z = 0; t.w = 0; }
                bfrag[nt] = *(bf16x8*)&t;
            }
            const int kt = (c0 / 32) * 9 + tap;
            const bf16x8* af = (const bf16x8*)wf + (size_t)kt * 4 * 64 + lane;
            bf16x8 afrag[4];
#pragma unroll
            for (int mt = 0; mt < 4; ++mt) afrag[mt] = af[(size_t)mt * 64];
#pragma unroll
            for (int mt = 0; mt < 4; ++mt)
#pragma unroll
                for (int nt = 0; nt < NT; ++nt)
                    acc[mt][nt] = __builtin_amdgcn_mfma_f32_16x16x32_bf16(
                        afrag[mt], bfrag[nt], acc[mt][nt], 0, 0, 0);
        }
    }

#pragma unroll
    for (int mt = 0; mt < 4; ++mt) {
        const int cout = mt * 16 + kb * 4;
        const float b0 = bias[cout], b1 = bias[cout + 1];
        const float b2 = bias[cout + 2], b3 = bias[cout + 3];
#pragma unroll
        for (int nt = 0; nt < NT; ++nt) {
            const int px = x0 + nt * 16 + ln;
            const size_t pix = (size_t)b * HWSZ + (size_t)y * WWID + px;
            f32x4 v = acc[mt][nt];
            v[0] += b0; v[1] += b1; v[2] += b2; v[3] += b3;
            if (LRELU) {
#pragma unroll
                for (int r = 0; r < 4; ++r) v[r] = (v[r] >= 0.f) ? v[r] : 0.1f * v[r];
            }
            int2 pk;
            pk.x = (int)f2bf(v[0]) | ((int)f2bf(v[1]) << 16);
            pk.y = (int)f2bf(v[2]) | ((int)f2bf(v[3]) << 16);
            *(int2*)(dst + pix * COUT + cout) = pk;
        }
    }
}

// ---------------------------------------------------------------------------
// FUSED conv_om + DCN. Block = 64 pixels (half row), 4 waves, grid 1024.
// Phase 1: om[216][64] implicit-GEMM -> LDS fp16 (stride 226).
// Phase 2: each wave owns 16 pixels, FULL K (18 steps), 2-stage software
//          pipeline: PREP(s+1) issues gathers while CONSUME(s) does
//          interpolation + MFMA. No K-split, no reduce.
// ---------------------------------------------------------------------------
__global__ __launch_bounds__(256) void dcn_fused_kernel(
    const unsigned short* __restrict__ off_f,   // NHWC bf16 [B][H][W][64]
    const unsigned short* __restrict__ nbr64,   // NHWC bf16 [B][H][W][64]
    const unsigned short* __restrict__ wf2,     // om A-frags (MT=14)
    const float* __restrict__ bom,
    const unsigned short* __restrict__ wdf,     // dcn A-frags
    const float* __restrict__ bdcn,
    float* __restrict__ out)
{
    __shared__ __half smem_h[64 * OMS];         // 28,928 B

    const int raw = blockIdx.x;                 // 0..1023
    const int bid = (raw & 7) * 128 + (raw >> 3);   // XCD-contiguous
    const int b = bid >> 8;
    const int rem = bid & 255;
    const int y = rem >> 1;
    const int x0 = (rem & 1) * 64;

    const int tid = threadIdx.x;
    const int lane = tid & 63;
    const int wv = tid >> 6;
    const int ln = lane & 15, kb = lane >> 4;

    // ---------------- Phase 1: om GEMM (M=224 pad, N=64, K=576) -----------
    f32x4 acc1[4][4];
#pragma unroll
    for (int i = 0; i < 4; ++i)
#pragma unroll
        for (int j = 0; j < 4; ++j) acc1[i][j] = f32x4{0.f, 0.f, 0.f, 0.f};

    {
        const unsigned short* inb = off_f + (size_t)b * HWSZ * 64 + (size_t)kb * 8;
        for (int c0 = 0; c0 < 64; c0 += 32) {
#pragma unroll
            for (int tap = 0; tap < 9; ++tap) {
                const int ky = tap / 3, kx = tap % 3;
                const int yy = y + ky - 1;
                const bool rowv = (unsigned)yy < (unsigned)HH;
                const int yc = rowv ? yy : 0;
                const unsigned short* rowp = inb + (size_t)yc * WWID * 64 + c0;
                bf16x8 bfrag[4];
#pragma unroll
                for (int nt = 0; nt < 4; ++nt) {
                    int xx = x0 + nt * 16 + ln + kx - 1;
                    bool v = rowv && ((unsigned)xx < (unsigned)WWID);
                    int xc = v ? xx : 0;
                    int4 t = *(const int4*)(rowp + (size_t)xc * 64);
                    if (!v) { t.x = 0; t.y = 0; t.z = 0; t.w = 0; }
                    bfrag[nt] = *(bf16x8*)&t;
                }
                const int kt = (c0 / 32) * 9 + tap;
                const bf16x8* af = (const bf16x8*)wf2 + (size_t)kt * 14 * 64 + lane;
#pragma unroll
                for (int i = 0; i < 4; ++i) {
                    const int mt = wv + 4 * i;
                    if (mt < 14) {
                        bf16x8 a = af[(size_t)mt * 64];
#pragma unroll
                        for (int nt = 0; nt < 4; ++nt)
                            acc1[i][nt] = __builtin_amdgcn_mfma_f32_16x16x32_bf16(
                                a, bfrag[nt], acc1[i][nt], 0, 0, 0);
                    }
                }
            }
        }
    }

    // epilogue: om -> LDS fp16 (+bias)
#pragma unroll
    for (int i = 0; i < 4; ++i) {
        const int mt = wv + 4 * i;
        if (mt >= 14) continue;
        const int cb = mt * 16 + kb * 4;
#pragma unroll
        for (int nt = 0; nt < 4; ++nt) {
            const int px = nt * 16 + ln;
#pragma unroll
            for (int r = 0; r < 4; ++r) {
                const int c = cb + r;
                if (c < C_OM)
                    smem_h[px * OMS + c] = __float2half(acc1[i][nt][r] + bom[c]);
            }
        }
    }
    __syncthreads();

    // ---------------- Phase 2: sampling + einsum, 2-stage pipeline ---------
    const int pxl = wv * 16 + ln;      // 0..63
    const int x = x0 + pxl;

    f32x4 acc[4];
#pragma unroll
    for (int mt = 0; mt < 4; ++mt) acc[mt] = f32x4{0.f, 0.f, 0.f, 0.f};

    const unsigned short* gb0 = nbr64 + (size_t)b * HWSZ * 64;

    int4 rgA[4], rgB[4];
    float wtA[4], wtB[4];

#define PREP(S, RG, WT) do {                                                  \
    const int gk = (S) * 4 + kb;                                              \
    const int g = gk / 9;                                                     \
    const int kt = gk - g * 9;                                                \
    const float oy = __half2float(smem_h[pxl * OMS + gk]);                    \
    const float ox = __half2float(smem_h[pxl * OMS + 72 + gk]);               \
    const float mr = __half2float(smem_h[pxl * OMS + 144 + gk]);              \
    const float mv = 1.f / (1.f + __expf(-mr));                               \
    const float pyf = (float)(y + kt / 3 - 1) + oy;                           \
    const float pxf = (float)(x + kt % 3 - 1) + ox;                           \
    const float fy = floorf(pyf), fx = floorf(pxf);                           \
    const float wy = pyf - fy, wx = pxf - fx;                                 \
    const int iy = (int)fy, ix = (int)fx;                                     \
    float w00 = (1.f - wy) * (1.f - wx);                                      \
    float w01 = (1.f - wy) * wx;                                              \
    float w10 = wy * (1.f - wx);                                              \
    float w11 = wy * wx;                                                      \
    const bool vy0 = (iy >= 0) && (iy < HH);                                  \
    const bool vy1 = (iy + 1 >= 0) && (iy + 1 < HH);                          \
    const bool vx0 = (ix >= 0) && (ix < WWID);                                \
    const bool vx1 = (ix + 1 >= 0) && (ix + 1 < WWID);                        \
    w00 *= (vy0 && vx0) ? mv : 0.f;                                           \
    w01 *= (vy0 && vx1) ? mv : 0.f;                                           \
    w10 *= (vy1 && vx0) ? mv : 0.f;                                           \
    w11 *= (vy1 && vx1) ? mv : 0.f;                                           \
    const int y0c = min(max(iy, 0), HH - 1);                                  \
    const int y1c = min(max(iy + 1, 0), HH - 1);                              \
    const int x0c = min(max(ix, 0), WWID - 1);                                \
    const int x1c = min(max(ix + 1, 0), WWID - 1);                            \
    const unsigned short* gb = gb0 + g * 8;                                   \
    RG[0] = *(const int4*)(gb + (size_t)(y0c * WWID + x0c) * 64);             \
    RG[1] = *(const int4*)(gb + (size_t)(y0c * WWID + x1c) * 64);             \
    RG[2] = *(const int4*)(gb + (size_t)(y1c * WWID + x0c) * 64);             \
    RG[3] = *(const int4*)(gb + (size_t)(y1c * WWID + x1c) * 64);             \
    WT[0] = w00; WT[1] = w01; WT[2] = w10; WT[3] = w11;                       \
} while (0)

#define CONSUME(S, RG, WT) do {                                               \
    const unsigned short* p00 = (const unsigned short*)&RG[0];                \
    const unsigned short* p01 = (const unsigned short*)&RG[1];                \
    const unsigned short* p10 = (const unsigned short*)&RG[2];                \
    const unsigned short* p11 = (const unsigned short*)&RG[3];                \
    union { bf16x8 v; unsigned short u[8]; } bp;                              \
    _Pragma("unroll")                                                         \
    for (int c = 0; c < 8; ++c) {                                             \
        float sv = WT[0] * bf2f(p00[c]) + WT[1] * bf2f(p01[c])                \
                 + WT[2] * bf2f(p10[c]) + WT[3] * bf2f(p11[c]);               \
        bp.u[c] = f2bf(sv);                                                   \
    }                                                                         \
    const bf16x8* af = (const bf16x8*)wdf + ((size_t)(S) * 4) * 64 + lane;    \
    _Pragma("unroll")                                                         \
    for (int mt = 0; mt < 4; ++mt)                                            \
        acc[mt] = __builtin_amdgcn_mfma_f32_16x16x32_bf16(                    \
            af[(size_t)mt * 64], bp.v, acc[mt], 0, 0, 0);                     \
} while (0)

    PREP(0, rgA, wtA);
#pragma unroll
    for (int s = 0; s < 18; ++s) {
        if (s & 1) {
            if (s < 17) PREP(s + 1, rgA, wtA);
            CONSUME(s, rgB, wtB);
        } else {
            if (s < 17) PREP(s + 1, rgB, wtB);
            CONSUME(s, rgA, wtA);
        }
    }
#undef PREP
#undef CONSUME

    // ---------------- Epilogue: direct store (no reduce) -------------------
#pragma unroll
    for (int mt = 0; mt < 4; ++mt) {
#pragma unroll
        for (int r = 0; r < 4; ++r) {
            const int cout = mt * 16 + kb * 4 + r;
            float v = acc[mt][r] + bdcn[cout];
            v = (v >= 0.f) ? v : 0.1f * v;
            out[((size_t)(b * NF + cout)) * HWSZ + (size_t)y * WWID + x] = v;
        }
    }
}

// ---------------------------------------------------------------------------
extern "C" void kernel_launch(void* const* d_in, const int* in_sizes, int n_in,
                              void* d_out, int out_size, void* d_ws, size_t ws_size,
                              hipStream_t stream)
{
    const float* nbr  = (const float*)d_in[0];
    const float* ref  = (const float*)d_in[1];
    const float* w1   = (const float*)d_in[2];
    const float* b1   = (const float*)d_in[3];
    const float* wom  = (const float*)d_in[4];
    const float* bom  = (const float*)d_in[5];
    const float* wdcn = (const float*)d_in[6];
    const float* bdcn = (const float*)d_in[7];
    float* out = (float*)d_out;

    const size_t NH_B  = (size_t)BB * HWSZ * 128 * 2;   // 16,777,216
    const size_t OFF_B = (size_t)BB * HWSZ * 64 * 2;    //  8,388,608
    const size_t N64_B = (size_t)BB * HWSZ * 64 * 2;    //  8,388,608
    const size_t WF1_B = 36 * 4 * 512 * 2;              //    147,456
    const size_t WF2_B = 18 * 14 * 512 * 2;             //    258,048

    char* ws = (char*)d_ws;
    unsigned short* nhwcin = (unsigned short*)ws;
    unsigned short* off_f  = (unsigned short*)(ws + NH_B);
    unsigned short* nbr64  = (unsigned short*)(ws + NH_B + OFF_B);
    unsigned short* wf1    = (unsigned short*)(ws + NH_B + OFF_B + N64_B);
    unsigned short* wf2    = wf1 + WF1_B / 2;
    unsigned short* wdf    = wf2 + WF2_B / 2;

    // 1) transpose: concat NHWC128 + compact nbr NHWC64
    to_nhwc_kernel<<<BB * HH * 2, 256, 0, stream>>>(nbr, ref, nhwcin, nbr64);

    // 2) all weight repacks (one launch)
    repack_all_kernel<<<936, 256, 0, stream>>>(w1, wom, wdcn, wf1, wf2, wdf);

    // 3) conv1: 128ch -> 64ch + lrelu, NHWC bf16
    conv_mfma_kernel<128, NF, true, 2><<<512, 256, 0, stream>>>(
        nhwcin, wf1, b1, off_f);

    // 4) fused conv_om + deformable conv (64-px blocks, full-K waves)
    dcn_fused_kernel<<<1024, 256, 0, stream>>>(
        off_f, nbr64, wf2, bom, wdf, bdcn, out);
}

// Round 6
// 133.436 us; speedup vs baseline: 1.2136x; 1.2136x over previous
//
#include <hip/hip_runtime.h>
#include <hip/hip_bf16.h>
#include <hip/hip_fp16.h>
#include <cmath>

#define NF 64
#define GRP 8
#define CG 8
#define KK 9
#define HH 128
#define WWID 128
#define BB 4
#define HWSZ (HH * WWID)
#define C_OM 216
#define OMSTR 292   // halfs per pixel in om LDS: 72 quads + pad (8B aligned, bank-spread)

typedef __attribute__((ext_vector_type(8))) short bf16x8;
typedef __attribute__((ext_vector_type(4))) float f32x4;

__device__ inline unsigned short f2bf(float f) {
    union { float f; unsigned u; } x; x.f = f;
    unsigned r = x.u + 0x7fff + ((x.u >> 16) & 1);   // RNE
    return (unsigned short)(r >> 16);
}
__device__ inline float bf2f(unsigned short s) {
    union { unsigned u; float f; } x; x.u = ((unsigned)s) << 16; return x.f;
}

// ---------------------------------------------------------------------------
// NCHW fp32 (nbr ++ ref) -> NHWC bf16 [B][H][W][128]  +  group-major
// gather buffer gm[B][G][H][W][8ch] bf16 (16B records).
// ---------------------------------------------------------------------------
__global__ __launch_bounds__(256) void to_nhwc_kernel(
    const float* __restrict__ nbr, const float* __restrict__ ref,
    unsigned short* __restrict__ out, unsigned short* __restrict__ gm)
{
    __shared__ unsigned short lds[64 * 136];
    const int tid = threadIdx.x, blk = blockIdx.x;
    const int b = blk >> 8, rem = blk & 255, y = rem >> 1, x0 = (rem & 1) * 64;
    const size_t rowoff = (size_t)y * WWID + x0;

    for (int it = 0; it < 32; ++it) {
        int idx = it * 256 + tid;
        int c = idx >> 6, p = idx & 63;
        const float* src = (c < NF) ? (nbr + (size_t)(b * NF + c) * HWSZ)
                                    : (ref + (size_t)(b * NF + c - NF) * HWSZ);
        lds[p * 136 + c] = f2bf(src[rowoff + p]);
    }
    __syncthreads();
    const int p = tid >> 2, c0 = (tid & 3) * 32;
    unsigned short* dst = out + ((size_t)b * HWSZ + rowoff + p) * 128 + c0;
#pragma unroll
    for (int i = 0; i < 8; ++i)
        *(int2*)(dst + i * 4) = *(const int2*)&lds[p * 136 + c0 + i * 4];
    if (c0 < 64) {
#pragma unroll
        for (int gi = 0; gi < 4; ++gi) {
            const int g = (c0 >> 3) + gi;
            *(int4*)(gm + (((size_t)(b * 8 + g)) * HWSZ + rowoff + p) * 8) =
                *(const int4*)&lds[p * 136 + g * 8];
        }
    }
}

// ---------------------------------------------------------------------------
// All weight repacks in one launch.
// wf1: conv1 A-frags (CIN=128, COUT=64, MT=4),   73728 elems
// wf2: om   A-frags (CIN=64, COUT=216, MT=14),  129024 elems
// wdf: dcn  A-frags (K=(g*9+kt)*8+c),            36864 elems
// ---------------------------------------------------------------------------
__global__ void repack_all_kernel(const float* __restrict__ w1,
                                  const float* __restrict__ wom,
                                  const float* __restrict__ wdcn,
                                  unsigned short* __restrict__ wf1,
                                  unsigned short* __restrict__ wf2,
                                  unsigned short* __restrict__ wdf)
{
    int idx = blockIdx.x * 256 + threadIdx.x;
    if (idx < 73728) {
        int j = idx & 7, lane = (idx >> 3) & 63, t = idx >> 9;
        int mt = t % 4, kt = t / 4;
        int c0 = (kt / 9) * 32, tap = kt - (kt / 9) * 9;
        int cout = mt * 16 + (lane & 15);
        int cin = c0 + ((lane >> 4) * 8) + j;
        wf1[idx] = f2bf(w1[((size_t)cout * 128 + cin) * KK + tap]);
        return;
    }
    idx -= 73728;
    if (idx < 129024) {
        int j = idx & 7, lane = (idx >> 3) & 63, t = idx >> 9;
        int mt = t % 14, kt = t / 14;
        int c0 = (kt / 9) * 32, tap = kt - (kt / 9) * 9;
        int cout = mt * 16 + (lane & 15);
        int cin = c0 + ((lane >> 4) * 8) + j;
        float v = (cout < C_OM) ? wom[((size_t)cout * 64 + cin) * KK + tap] : 0.f;
        wf2[idx] = f2bf(v);
        return;
    }
    idx -= 129024;
    if (idx < 36864) {
        int j = idx & 7, lane = (idx >> 3) & 63, t = idx >> 9;
        int mt = t & 3, s = t >> 2;
        int cout = mt * 16 + (lane & 15);
        int kglob = s * 32 + (lane >> 4) * 8 + j;
        int gk = kglob >> 3, c = kglob & 7;
        int g = gk / 9, kt = gk - g * 9;
        wdf[idx] = f2bf(wdcn[((size_t)cout * NF + g * 8 + c) * 9 + kt]);
    }
}

// ---------------------------------------------------------------------------
// Implicit-GEMM 3x3 conv (conv1) via mfma_f32_16x16x32_bf16.
// ---------------------------------------------------------------------------
template <int CIN, int COUT, bool LRELU, int NT>
__global__ __launch_bounds__(256) void conv_mfma_kernel(
    const unsigned short* __restrict__ in,
    const unsigned short* __restrict__ wf,
    const float* __restrict__ bias,
    unsigned short* __restrict__ dst)
{
    const int tid = threadIdx.x;
    const int lane = tid & 63;
    const int wv = tid >> 6;
    const int ng = blockIdx.x * 4 + wv;
    constexpr int SEG = 128 / (16 * NT);
    const int x0 = (ng % SEG) * (16 * NT);
    const int y  = (ng / SEG) % 128;
    const int b  = ng / (SEG * 128);
    const int ln = lane & 15, kb = lane >> 4;

    f32x4 acc[4][NT];
#pragma unroll
    for (int i = 0; i < 4; ++i)
#pragma unroll
        for (int j = 0; j < NT; ++j) acc[i][j] = f32x4{0.f, 0.f, 0.f, 0.f};

    const unsigned short* inb = in + (size_t)b * HWSZ * CIN + (size_t)kb * 8;

    for (int c0 = 0; c0 < CIN; c0 += 32) {
#pragma unroll
        for (int tap = 0; tap < 9; ++tap) {
            const int ky = tap / 3, kx = tap % 3;
            const int yy = y + ky - 1;
            const bool rowv = (unsigned)yy < (unsigned)HH;
            const int yc = rowv ? yy : 0;
            const unsigned short* rowp = inb + (size_t)yc * WWID * CIN + c0;
            bf16x8 bfrag[NT];
#pragma unroll
            for (int nt = 0; nt < NT; ++nt) {
                int xx = x0 + nt * 16 + ln + kx - 1;
                bool v = rowv && ((unsigned)xx < (unsigned)WWID);
                int xc = v ? xx : 0;
                int4 t = *(const int4*)(rowp + (size_t)xc * CIN);
                if (!v) { t.x = 0; t.y = 0; t.z = 0; t.w = 0; }
                bfrag[nt] = *(bf16x8*)&t;
            }
            const int kt = (c0 / 32) * 9 + tap;
            const bf16x8* af = (const bf16x8*)wf + (size_t)kt * 4 * 64 + lane;
            bf16x8 afrag[4];
#pragma unroll
            for (int mt = 0; mt < 4; ++mt) afrag[mt] = af[(size_t)mt * 64];
#pragma unroll
            for (int mt = 0; mt < 4; ++mt)
#pragma unroll
                for (int nt = 0; nt < NT; ++nt)
                    acc[mt][nt] = __builtin_amdgcn_mfma_f32_16x16x32_bf16(
                        afrag[mt], bfrag[nt], acc[mt][nt], 0, 0, 0);
        }
    }

#pragma unroll
    for (int mt = 0; mt < 4; ++mt) {
        const int cout = mt * 16 + kb * 4;
        const float b0 = bias[cout], b1 = bias[cout + 1];
        const float b2 = bias[cout + 2], b3 = bias[cout + 3];
#pragma unroll
        for (int nt = 0; nt < NT; ++nt) {
            const int px = x0 + nt * 16 + ln;
            const size_t pix = (size_t)b * HWSZ + (size_t)y * WWID + px;
            f32x4 v = acc[mt][nt];
            v[0] += b0; v[1] += b1; v[2] += b2; v[3] += b3;
            if (LRELU) {
#pragma unroll
                for (int r = 0; r < 4; ++r) v[r] = (v[r] >= 0.f) ? v[r] : 0.1f * v[r];
            }
            int2 pk;
            pk.x = (int)f2bf(v[0]) | ((int)f2bf(v[1]) << 16);
            pk.y = (int)f2bf(v[2]) | ((int)f2bf(v[3]) << 16);
            *(int2*)(dst + pix * COUT + cout) = pk;
        }
    }
}

// ---------------------------------------------------------------------------
// FUSED conv_om + DCN. Block = 128 threads (2 waves), 32 pixels, grid 2048.
// Phase 1: om[216][32] implicit-GEMM -> LDS as fp16 (oy,ox,mr,pad) quads.
// Phase 2: each wave owns 16 pixels x full K; gathers from group-major
//          16B records with paired-corner loads (clamp folded into weights).
// ---------------------------------------------------------------------------
__global__ __launch_bounds__(128) void dcn_fused_kernel(
    const unsigned short* __restrict__ off_f,   // NHWC bf16 [B][H][W][64]
    const unsigned short* __restrict__ gm,      // gmajor bf16 [B][G][H][W][8]
    const unsigned short* __restrict__ wf2,     // om A-frags (MT=14)
    const float* __restrict__ bom,
    const unsigned short* __restrict__ wdf,     // dcn A-frags
    const float* __restrict__ bdcn,
    float* __restrict__ out)
{
    __shared__ __half smem_h[32 * OMSTR];       // 18,688 B

    const int raw = blockIdx.x;                 // 0..2047
    const int bid = (raw & 7) * 256 + (raw >> 3);   // XCD-contiguous
    const int b = bid >> 9;
    const int rem = bid & 511;
    const int y = rem >> 2;
    const int x0 = (rem & 3) * 32;

    const int tid = threadIdx.x;
    const int lane = tid & 63;
    const int wv = tid >> 6;                    // 0..1
    const int ln = lane & 15, kb = lane >> 4;

    // ---------------- Phase 1: om GEMM (M=224 pad, N=32, K=576) -----------
    f32x4 acc1[7][2];
#pragma unroll
    for (int i = 0; i < 7; ++i)
#pragma unroll
        for (int j = 0; j < 2; ++j) acc1[i][j] = f32x4{0.f, 0.f, 0.f, 0.f};

    {
        const unsigned short* inb = off_f + (size_t)b * HWSZ * 64 + (size_t)kb * 8;
        for (int c0 = 0; c0 < 64; c0 += 32) {
#pragma unroll
            for (int tap = 0; tap < 9; ++tap) {
                const int ky = tap / 3, kx = tap % 3;
                const int yy = y + ky - 1;
                const bool rowv = (unsigned)yy < (unsigned)HH;
                const int yc = rowv ? yy : 0;
                const unsigned short* rowp = inb + (size_t)yc * WWID * 64 + c0;
                bf16x8 bfrag[2];
#pragma unroll
                for (int nt = 0; nt < 2; ++nt) {
                    int xx = x0 + nt * 16 + ln + kx - 1;
                    bool v = rowv && ((unsigned)xx < (unsigned)WWID);
                    int xc = v ? xx : 0;
                    int4 t = *(const int4*)(rowp + (size_t)xc * 64);
                    if (!v) { t.x = 0; t.y = 0; t.z = 0; t.w = 0; }
                    bfrag[nt] = *(bf16x8*)&t;
                }
                const int kt = (c0 / 32) * 9 + tap;
                const bf16x8* af = (const bf16x8*)wf2 + (size_t)kt * 14 * 64 + lane;
#pragma unroll
                for (int i = 0; i < 7; ++i) {
                    const int mt = wv * 7 + i;
                    bf16x8 a = af[(size_t)mt * 64];
#pragma unroll
                    for (int nt = 0; nt < 2; ++nt)
                        acc1[i][nt] = __builtin_amdgcn_mfma_f32_16x16x32_bf16(
                            a, bfrag[nt], acc1[i][nt], 0, 0, 0);
                }
            }
        }
    }

    // epilogue: om -> LDS fp16 quads (oy,ox,mr,pad) per (pixel, gk)
#pragma unroll
    for (int i = 0; i < 7; ++i) {
        const int mt = wv * 7 + i;
        const int cb = mt * 16 + kb * 4;
#pragma unroll
        for (int nt = 0; nt < 2; ++nt) {
            const int px = nt * 16 + ln;
#pragma unroll
            for (int r = 0; r < 4; ++r) {
                const int c = cb + r;
                if (c < C_OM) {
                    const int field = (c >= 144) ? 2 : ((c >= 72) ? 1 : 0);
                    const int gk = c - field * 72;
                    smem_h[px * OMSTR + gk * 4 + field] =
                        __float2half(acc1[i][nt][r] + bom[c]);
                }
            }
        }
    }
    __syncthreads();

    // ---------------- Phase 2: sampling + einsum (full K per wave) ---------
    const int pxl = wv * 16 + ln;      // 0..31
    const int x = x0 + pxl;

    f32x4 acc[4];
#pragma unroll
    for (int mt = 0; mt < 4; ++mt) acc[mt] = f32x4{0.f, 0.f, 0.f, 0.f};

    const unsigned short* gmb = gm + (size_t)b * 8 * HWSZ * 8;

#pragma unroll 2
    for (int s = 0; s < 18; ++s) {
        const int gk = s * 4 + kb;
        const int g = gk / 9;
        const int kt = gk - g * 9;

        const short4 omq = *(const short4*)&smem_h[pxl * OMSTR + gk * 4];
        const float oy = __half2float(((const __half*)&omq)[0]);
        const float ox = __half2float(((const __half*)&omq)[1]);
        const float mr = __half2float(((const __half*)&omq)[2]);
        const float mv = 1.f / (1.f + __expf(-mr));

        const float pyf = (float)(y + kt / 3 - 1) + oy;
        const float pxf = (float)(x + kt % 3 - 1) + ox;
        const float fy = floorf(pyf), fx = floorf(pxf);
        const float wy = pyf - fy, wx = pxf - fx;
        const int iy = (int)fy, ix = (int)fx;

        float w00 = (1.f - wy) * (1.f - wx);
        float w01 = (1.f - wy) * wx;
        float w10 = wy * (1.f - wx);
        float w11 = wy * wx;

        const bool vy0 = (iy >= 0) && (iy < HH);
        const bool vy1 = (iy + 1 >= 0) && (iy + 1 < HH);
        const bool vx0 = (ix >= 0) && (ix < WWID);
        const bool vx1 = (ix + 1 >= 0) && (ix + 1 < WWID);
        w00 *= (vy0 && vx0) ? mv : 0.f;
        w01 *= (vy0 && vx1) ? mv : 0.f;
        w10 *= (vy1 && vx0) ? mv : 0.f;
        w11 *= (vy1 && vx1) ? mv : 0.f;

        const int y0c = min(max(iy, 0), HH - 1);
        const int y1c = min(max(iy + 1, 0), HH - 1);
        const int x0c = min(max(ix, 0), WWID - 1);
        const int x1c = min(max(ix + 1, 0), WWID - 1);
        const int sel = x1c - x0c;           // 0 or 1

        // fold x-corner selection into weights
        const float wl0 = w00 + (sel ? 0.f : w01);
        const float wh0 = sel ? w01 : 0.f;
        const float wl1 = w10 + (sel ? 0.f : w11);
        const float wh1 = sel ? w11 : 0.f;

        const unsigned short* pgm = gmb + (size_t)g * HWSZ * 8;
        const size_t rec0 = (size_t)(y0c * WWID + x0c) * 8;
        const size_t rec1 = (size_t)(y1c * WWID + x0c) * 8;
        int4 L0 = *(const int4*)(pgm + rec0);
        int4 H0 = *(const int4*)(pgm + rec0 + 8);
        int4 L1 = *(const int4*)(pgm + rec1);
        int4 H1 = *(const int4*)(pgm + rec1 + 8);
        const unsigned short* l0 = (const unsigned short*)&L0;
        const unsigned short* h0 = (const unsigned short*)&H0;
        const unsigned short* l1 = (const unsigned short*)&L1;
        const unsigned short* h1 = (const unsigned short*)&H1;

        union { bf16x8 v; unsigned short u[8]; } bp;
#pragma unroll
        for (int c = 0; c < 8; ++c) {
            float sv = wl0 * bf2f(l0[c]) + wh0 * bf2f(h0[c])
                     + wl1 * bf2f(l1[c]) + wh1 * bf2f(h1[c]);
            bp.u[c] = f2bf(sv);
        }

        const bf16x8* af = (const bf16x8*)wdf + ((size_t)s * 4) * 64 + lane;
#pragma unroll
        for (int mt = 0; mt < 4; ++mt)
            acc[mt] = __builtin_amdgcn_mfma_f32_16x16x32_bf16(
                af[(size_t)mt * 64], bp.v, acc[mt], 0, 0, 0);
    }

    // ---------------- Epilogue: direct store -------------------------------
#pragma unroll
    for (int mt = 0; mt < 4; ++mt) {
#pragma unroll
        for (int r = 0; r < 4; ++r) {
            const int cout = mt * 16 + kb * 4 + r;
            float v = acc[mt][r] + bdcn[cout];
            v = (v >= 0.f) ? v : 0.1f * v;
            out[((size_t)(b * NF + cout)) * HWSZ + (size_t)y * WWID + x] = v;
        }
    }
}

// ---------------------------------------------------------------------------
extern "C" void kernel_launch(void* const* d_in, const int* in_sizes, int n_in,
                              void* d_out, int out_size, void* d_ws, size_t ws_size,
                              hipStream_t stream)
{
    const float* nbr  = (const float*)d_in[0];
    const float* ref  = (const float*)d_in[1];
    const float* w1   = (const float*)d_in[2];
    const float* b1   = (const float*)d_in[3];
    const float* wom  = (const float*)d_in[4];
    const float* bom  = (const float*)d_in[5];
    const float* wdcn = (const float*)d_in[6];
    const float* bdcn = (const float*)d_in[7];
    float* out = (float*)d_out;

    const size_t NH_B  = (size_t)BB * HWSZ * 128 * 2;   // 16,777,216
    const size_t OFF_B = (size_t)BB * HWSZ * 64 * 2;    //  8,388,608
    const size_t GM_B  = (size_t)BB * HWSZ * 64 * 2 + 64; // + overread pad
    const size_t WF1_B = 36 * 4 * 512 * 2;              //    147,456
    const size_t WF2_B = 18 * 14 * 512 * 2;             //    258,048

    char* ws = (char*)d_ws;
    unsigned short* nhwcin = (unsigned short*)ws;
    unsigned short* off_f  = (unsigned short*)(ws + NH_B);
    unsigned short* gm     = (unsigned short*)(ws + NH_B + OFF_B);
    unsigned short* wf1    = (unsigned short*)(ws + NH_B + OFF_B + GM_B);
    unsigned short* wf2    = wf1 + WF1_B / 2;
    unsigned short* wdf    = wf2 + WF2_B / 2;

    // 1) transpose: concat NHWC128 + group-major gather buffer
    to_nhwc_kernel<<<BB * HH * 2, 256, 0, stream>>>(nbr, ref, nhwcin, gm);

    // 2) all weight repacks (one launch)
    repack_all_kernel<<<936, 256, 0, stream>>>(w1, wom, wdcn, wf1, wf2, wdf);

    // 3) conv1: 128ch -> 64ch + lrelu, NHWC bf16
    conv_mfma_kernel<128, NF, true, 2><<<512, 256, 0, stream>>>(
        nhwcin, wf1, b1, off_f);

    // 4) fused conv_om + deformable conv (32-px blocks, 2 waves, full-K)
    dcn_fused_kernel<<<2048, 128, 0, stream>>>(
        off_f, gm, wf2, bom, wdf, bdcn, out);
}